// Round 5
// baseline (708.127 us; speedup 1.0000x reference)
//
#include <hip/hip_runtime.h>

// Sizes
#define Gg   128
#define N1   512
#define FH   128
#define K1   256
#define K2   128

typedef unsigned short ush;
typedef __bf16 bf16x8 __attribute__((ext_vector_type(8)));
typedef float  floatx4 __attribute__((ext_vector_type(4)));

__device__ inline float wredsum(float v) {
#pragma unroll
    for (int o = 32; o; o >>= 1) v += __shfl_xor(v, o, 64);
    return v;
}
__device__ inline float wredmax(float v) {
#pragma unroll
    for (int o = 32; o; o >>= 1) v = fmaxf(v, __shfl_xor(v, o, 64));
    return v;
}
__device__ inline ush bf_rne(float x) {
    unsigned u = __float_as_uint(x);
    return (ush)((u + 0x7fffu + ((u >> 16) & 1u)) >> 16);
}
__device__ inline float bf2f(ush u) { return __uint_as_float((unsigned)u << 16); }
__device__ inline void split3(float v, ush& h, ush& m, ush& l) {
    h = bf_rne(v);
    float r1 = v - bf2f(h);
    m = bf_rne(r1);
    l = bf_rne(r1 - bf2f(m));
}

// ---------------------------------------------------------------------------
// prep: degrees + 1-bit packed adjacency (adj values exactly 0/1)
// adjbits[row][w] bit c = adj[row][w*32+c] != 0
// ---------------------------------------------------------------------------
__global__ __launch_bounds__(256) void k_prep(const float* __restrict__ adj,
        float* __restrict__ dinv_gcn, float* __restrict__ dinv_info,
        unsigned* __restrict__ adjbits) {
    int wave = threadIdx.x >> 6, lane = threadIdx.x & 63;
    long long row = (long long)blockIdx.x * 4 + wave;
    const float* ar = adj + row * N1;
    float s = 0.f;
    unsigned myw = 0;
#pragma unroll
    for (int c = 0; c < 8; ++c) {
        float v = ar[c * 64 + lane];
        s += v;
        unsigned long long mk = __ballot(v != 0.0f);
        unsigned lo = (unsigned)mk, hi = (unsigned)(mk >> 32);
        if ((lane >> 1) == c) myw = (lane & 1) ? hi : lo;
    }
    if (lane < 16) adjbits[row * 16 + lane] = myw;
    s = wredsum(s);
    if (lane == 0) {
        dinv_gcn[row]  = rsqrtf(s + 1.0f);
        dinv_info[row] = 1.0f / fmaxf(s, 1.0f);
    }
}

// ---------------------------------------------------------------------------
// Row-weight GEMM: C[M,128] = rs[row] * (A[M,128] @ W[128,128])  (rs optional)
// ---------------------------------------------------------------------------
__global__ __launch_bounds__(256) void k_gemm_rw(const float* __restrict__ A,
        const float* __restrict__ W, float* __restrict__ C,
        const float* __restrict__ rs) {
    __shared__ float Al[64][68];
    __shared__ float Wl[64][132];
    long long row0 = (long long)blockIdx.x * 64;
    int tid = threadIdx.x, tr = tid >> 4, tc = tid & 15;
    float acc[4][8] = {};
    for (int ch = 0; ch < 2; ++ch) {
        for (int p = tid; p < 1024; p += 256) {
            int r = p >> 4, c4 = p & 15;
            *(float4*)&Al[r][c4 * 4] = *(const float4*)(A + (row0 + r) * 128 + ch * 64 + c4 * 4);
        }
        for (int p = tid; p < 2048; p += 256) {
            int r = p >> 5, c4 = p & 31;
            *(float4*)&Wl[r][c4 * 4] = *(const float4*)(W + (ch * 64 + r) * 128 + c4 * 4);
        }
        __syncthreads();
        for (int k = 0; k < 64; ++k) {
            float4 w0 = *(const float4*)&Wl[k][tc * 8];
            float4 w1 = *(const float4*)&Wl[k][tc * 8 + 4];
            float w[8] = {w0.x, w0.y, w0.z, w0.w, w1.x, w1.y, w1.z, w1.w};
#pragma unroll
            for (int i = 0; i < 4; ++i) {
                float a = Al[tr * 4 + i][k];
#pragma unroll
                for (int j = 0; j < 8; ++j) acc[i][j] = fmaf(a, w[j], acc[i][j]);
            }
        }
        __syncthreads();
    }
#pragma unroll
    for (int i = 0; i < 4; ++i) {
        long long r = row0 + tr * 4 + i;
        float sc = rs ? rs[r] : 1.0f;
        *(float4*)(C + r * 128 + tc * 8)     = make_float4(sc * acc[i][0], sc * acc[i][1], sc * acc[i][2], sc * acc[i][3]);
        *(float4*)(C + r * 128 + tc * 8 + 4) = make_float4(sc * acc[i][4], sc * acc[i][5], sc * acc[i][6], sc * acc[i][7]);
    }
}

// ---------------------------------------------------------------------------
// transpose + 3-way bf16 split: feat[g*512][128] fp32 -> T{hi,mid,lo}[g][128][512]
// ---------------------------------------------------------------------------
__global__ __launch_bounds__(256) void k_tsplit(const float* __restrict__ feat,
        ush* __restrict__ Thi, ush* __restrict__ Tmid, ush* __restrict__ Tlo) {
    __shared__ float tile[64 * 65];
    int b = blockIdx.x;                    // G * 8 * 2
    int g = b >> 4, rb = (b >> 1) & 7, cb = b & 1;
    int t = threadIdx.x;
    {
        int r0 = t >> 4, c4 = t & 15;
#pragma unroll
        for (int i = 0; i < 4; ++i) {
            int r = r0 + i * 16;
            float4 v = *(const float4*)(feat + ((long long)g * 512 + rb * 64 + r) * 128 + cb * 64 + c4 * 4);
            tile[r * 65 + c4 * 4 + 0] = v.x;
            tile[r * 65 + c4 * 4 + 1] = v.y;
            tile[r * 65 + c4 * 4 + 2] = v.z;
            tile[r * 65 + c4 * 4 + 3] = v.w;
        }
    }
    __syncthreads();
    int tf = t >> 2, chunk = t & 3;
    ush hbuf[16] __attribute__((aligned(16)));
    ush mbuf[16] __attribute__((aligned(16)));
    ush lbuf[16] __attribute__((aligned(16)));
#pragma unroll
    for (int i = 0; i < 16; ++i) {
        int m = chunk * 16 + i;
        split3(tile[m * 65 + tf], hbuf[i], mbuf[i], lbuf[i]);
    }
    long long obase = ((long long)g * 128 + cb * 64 + tf) * 512 + rb * 64 + chunk * 16;
    *(uint4*)(Thi + obase)      = *(const uint4*)&hbuf[0];
    *(uint4*)(Thi + obase + 8)  = *(const uint4*)&hbuf[8];
    *(uint4*)(Tmid + obase)     = *(const uint4*)&mbuf[0];
    *(uint4*)(Tmid + obase + 8) = *(const uint4*)&mbuf[8];
    *(uint4*)(Tlo + obase)      = *(const uint4*)&lbuf[0];
    *(uint4*)(Tlo + obase + 8)  = *(const uint4*)&lbuf[8];
}

// ---------------------------------------------------------------------------
// bit-A MFMA aggregation: C = adj(bits, exact) @ (Bhi+Bmid+Blo)[g][128][512]
//  64-row x 128-col blocks, 4 waves (2x2 of 32x64). NO LDS staging / NO
//  barriers in the K-loop: A expanded from bits in registers, B fragments
//  loaded per-lane directly from global (k-major layout matches B-operand).
//  EPI 0 (gcn):  outH = relu(di*(C+hx)+bias)   (in-place over hx ok)
//  EPI 1 (info): outS_i = sum_n |hx - C*di|
// ---------------------------------------------------------------------------
template<int EPI>
__global__ __launch_bounds__(256) void k_aggb(const unsigned* __restrict__ adjbits,
        const ush* __restrict__ Bhi, const ush* __restrict__ Bmid, const ush* __restrict__ Blo,
        const float* __restrict__ dvec, const float* __restrict__ hx,
        const float* __restrict__ bias, float* __restrict__ outH, float* __restrict__ outS) {
    __shared__ unsigned bitsL[64 * 17];
    __shared__ float sred[2][64];
    int b = blockIdx.x;                        // 1024
    int g  = (b & 7) + ((b >> 6) << 3);        // 8 row-blocks of graph g on XCD g%8
    int rb = (b >> 3) & 7;
    int tid = threadIdx.x;
    int w = tid >> 6, lane = tid & 63;
    int wm = w >> 1, wn = w & 1;
    int ln = lane & 15, quad = lane >> 4;
    // stage this block's 64 rows of adjacency bits (once; padded stride 17)
    {
        int r = tid >> 2, w4 = (tid & 3) * 4;
        uint4 v = *(const uint4*)(adjbits + ((long long)(g * 512 + rb * 64 + r)) * 16 + w4);
        bitsL[r * 17 + w4 + 0] = v.x; bitsL[r * 17 + w4 + 1] = v.y;
        bitsL[r * 17 + w4 + 2] = v.z; bitsL[r * 17 + w4 + 3] = v.w;
    }
    __syncthreads();
    floatx4 acc[2][4];
#pragma unroll
    for (int i = 0; i < 2; ++i)
#pragma unroll
        for (int j = 0; j < 4; ++j) { floatx4 z = {0.f, 0.f, 0.f, 0.f}; acc[i][j] = z; }

    const long long bb = (long long)g * 128 * 512;
    for (int kt = 0; kt < 16; ++kt) {
        int kk = kt * 32;
        bf16x8 af[2];
#pragma unroll
        for (int tm = 0; tm < 2; ++tm) {
            unsigned word = bitsL[(wm * 32 + tm * 16 + ln) * 17 + kt];  // quad-broadcast
            unsigned byte = (word >> (quad * 8)) & 0xffu;
            unsigned au[4] __attribute__((aligned(16)));
            au[0] = ((byte >> 0) & 1 ? 0x3F80u : 0u) | ((byte >> 1) & 1 ? 0x3F800000u : 0u);
            au[1] = ((byte >> 2) & 1 ? 0x3F80u : 0u) | ((byte >> 3) & 1 ? 0x3F800000u : 0u);
            au[2] = ((byte >> 4) & 1 ? 0x3F80u : 0u) | ((byte >> 5) & 1 ? 0x3F800000u : 0u);
            au[3] = ((byte >> 6) & 1 ? 0x3F80u : 0u) | ((byte >> 7) & 1 ? 0x3F800000u : 0u);
            af[tm] = *(const bf16x8*)au;
        }
#pragma unroll
        for (int tn = 0; tn < 4; ++tn) {
            long long off = bb + (long long)(wn * 64 + tn * 16 + ln) * 512 + kk + quad * 8;
            bf16x8 bh = *(const bf16x8*)(Bhi + off);
            bf16x8 bm = *(const bf16x8*)(Bmid + off);
            bf16x8 bl = *(const bf16x8*)(Blo + off);
#pragma unroll
            for (int tm = 0; tm < 2; ++tm) {
                acc[tm][tn] = __builtin_amdgcn_mfma_f32_16x16x32_bf16(af[tm], bh, acc[tm][tn], 0, 0, 0);
                acc[tm][tn] = __builtin_amdgcn_mfma_f32_16x16x32_bf16(af[tm], bm, acc[tm][tn], 0, 0, 0);
                acc[tm][tn] = __builtin_amdgcn_mfma_f32_16x16x32_bf16(af[tm], bl, acc[tm][tn], 0, 0, 0);
            }
        }
    }
    long long rowbase = (long long)g * 512 + rb * 64;
    if (EPI == 0) {
#pragma unroll
        for (int tm = 0; tm < 2; ++tm)
#pragma unroll
        for (int r = 0; r < 4; ++r) {
            long long grow = rowbase + wm * 32 + tm * 16 + quad * 4 + r;
            float di = dvec[grow];
#pragma unroll
            for (int tn = 0; tn < 4; ++tn) {
                int nc = wn * 64 + tn * 16 + ln;
                outH[grow * 128 + nc] =
                    fmaxf(fmaf(di, acc[tm][tn][r] + hx[grow * 128 + nc], bias[nc]), 0.f);
            }
        }
    } else {
#pragma unroll
        for (int tm = 0; tm < 2; ++tm)
#pragma unroll
        for (int r = 0; r < 4; ++r) {
            int ml = wm * 32 + tm * 16 + quad * 4 + r;
            long long grow = rowbase + ml;
            float di = dvec[grow];
            float v = 0.f;
#pragma unroll
            for (int tn = 0; tn < 4; ++tn) {
                int nc = wn * 64 + tn * 16 + ln;
                v += fabsf(hx[grow * 128 + nc] - acc[tm][tn][r] * di);
            }
            v += __shfl_xor(v, 1); v += __shfl_xor(v, 2);
            v += __shfl_xor(v, 4); v += __shfl_xor(v, 8);
            if (ln == 0) sred[wn][ml] = v;
        }
        __syncthreads();
        if (tid < 64) outS[rowbase + tid] = sred[0][tid] + sred[1][tid];
    }
}

// ---------------------------------------------------------------------------
// top-k: bitonic sort of packed keys -> value desc, index asc (jax.lax.top_k)
// ---------------------------------------------------------------------------
template<int NT, int KSEL>
__global__ __launch_bounds__(256) void k_topk(const float* __restrict__ s, int* __restrict__ idx) {
    __shared__ unsigned long long keys[NT];
    int g = blockIdx.x;
    const float* sg = s + g * NT;
    for (int t = threadIdx.x; t < NT; t += 256) {
        unsigned int b = __float_as_uint(sg[t]);
        unsigned int ord = (b & 0x80000000u) ? ~b : (b | 0x80000000u);
        keys[t] = ((unsigned long long)(~ord) << 32) | (unsigned int)t;
    }
    __syncthreads();
    for (int k = 2; k <= NT; k <<= 1) {
        for (int j = k >> 1; j > 0; j >>= 1) {
            for (int i = threadIdx.x; i < NT; i += 256) {
                int l = i ^ j;
                if (l > i) {
                    bool dir = ((i & k) == 0);
                    unsigned long long a = keys[i], b2 = keys[l];
                    bool sw = dir ? (a > b2) : (a < b2);
                    if (sw) { keys[i] = b2; keys[l] = a; }
                }
            }
            __syncthreads();
        }
    }
    for (int t = threadIdx.x; t < KSEL; t += 256)
        idx[g * KSEL + t] = (int)(keys[t] & 0xffffffffu);
}

// ---------------------------------------------------------------------------
// gather pooled rows + attention dot products
// ---------------------------------------------------------------------------
template<int KK>
__global__ __launch_bounds__(256) void k_gather(const float* __restrict__ h, int srcN,
        const int* __restrict__ idx, const float* __restrict__ atts, const float* __restrict__ attd,
        float* __restrict__ xk, float* __restrict__ as_, float* __restrict__ ad_) {
    int wave = threadIdx.x >> 6, lane = threadIdx.x & 63;
    int r = blockIdx.x * 4 + wave;
    int g = r / KK;
    int j = idx[r];
    float2 v = *(const float2*)(h + ((long long)g * srcN + j) * 128 + lane * 2);
    *(float2*)(xk + (long long)r * 128 + lane * 2) = v;
    float2 sv = *(const float2*)(atts + lane * 2);
    float2 dv = *(const float2*)(attd + lane * 2);
    float ps = v.x * sv.x + v.y * sv.y;
    float pd = v.x * dv.x + v.y * dv.y;
    ps = wredsum(ps); pd = wredsum(pd);
    if (lane == 0) { as_[r] = ps; ad_[r] = pd; }
}

// ---------------------------------------------------------------------------
// attention stage-1 (bit adjacency): softmax(leaky(as_i+ad_j) + bit(idx_i,idx_j))
// ---------------------------------------------------------------------------
__global__ __launch_bounds__(256) void k_attn1b(const unsigned* __restrict__ adjbits,
        const int* __restrict__ idx, const float* __restrict__ as_, const float* __restrict__ ad_,
        float* __restrict__ a1, float* __restrict__ dgo, float* __restrict__ dio) {
    __shared__ int   idxL[K1];
    __shared__ float adL[K1];
    __shared__ unsigned bitsW[4][20];
    int g = blockIdx.x / (K1 / 4);
    int wave = threadIdx.x >> 6, lane = threadIdx.x & 63;
    int i = (blockIdx.x % (K1 / 4)) * 4 + wave;
    for (int t = threadIdx.x; t < K1; t += 256) { idxL[t] = idx[g * K1 + t]; adL[t] = ad_[g * K1 + t]; }
    __syncthreads();
    int ri = idxL[i];
    if (lane < 4) {
        uint4 v = *(const uint4*)(adjbits + ((long long)(g * 512 + ri)) * 16 + lane * 4);
        bitsW[wave][lane * 4 + 0] = v.x; bitsW[wave][lane * 4 + 1] = v.y;
        bitsW[wave][lane * 4 + 2] = v.z; bitsW[wave][lane * 4 + 3] = v.w;
    }
    __syncthreads();
    float asi = as_[g * K1 + i];
    float vals[4];
    float m = -1e30f;
#pragma unroll
    for (int e = 0; e < 4; ++e) {
        int j = e * 64 + lane;
        float x = asi + adL[j];
        x = (x >= 0.f) ? x : 0.2f * x;
        int jj = idxL[j];
        unsigned bit = (bitsW[wave][jj >> 5] >> (jj & 31)) & 1u;
        x += (float)bit;                    // LAMB = 1.0, adj exactly 0/1
        vals[e] = x; m = fmaxf(m, x);
    }
    m = wredmax(m);
    float S = 0.f;
#pragma unroll
    for (int e = 0; e < 4; ++e) { vals[e] = expf(vals[e] - m); S += vals[e]; }
    S = wredsum(S);
    float inv = 1.f / S, rs = 0.f;
    float* orow = a1 + ((long long)g * K1 + i) * K1;
#pragma unroll
    for (int e = 0; e < 4; ++e) { float p = vals[e] * inv; rs += p; orow[e * 64 + lane] = p; }
    rs = wredsum(rs);
    if (lane == 0) { dgo[g * K1 + i] = rsqrtf(rs + 1.f); dio[g * K1 + i] = 1.f / fmaxf(rs, 1.f); }
}

// ---------------------------------------------------------------------------
// attention (dense fp32 source adjacency) + deg epilogue
// ---------------------------------------------------------------------------
template<int KK, int SRCN>
__global__ __launch_bounds__(256) void k_attn(const float* __restrict__ adjSrc,
        const int* __restrict__ idx, const float* __restrict__ as_, const float* __restrict__ ad_,
        float* __restrict__ attn, float* __restrict__ dgo, float* __restrict__ dio) {
    constexpr int E = KK / 64;
    __shared__ int   idxL[KK];
    __shared__ float adL[KK];
    __shared__ float rowL[4][SRCN];
    int bpg = KK / 4;
    int g = blockIdx.x / bpg;
    int wave = threadIdx.x >> 6, lane = threadIdx.x & 63;
    int i = (blockIdx.x % bpg) * 4 + wave;
    for (int t = threadIdx.x; t < KK; t += 256) { idxL[t] = idx[g * KK + t]; adL[t] = ad_[g * KK + t]; }
    __syncthreads();
    int ri = idxL[i];
    const float* arow = adjSrc + ((long long)g * SRCN + ri) * SRCN;
    for (int c = lane; c < SRCN; c += 64) rowL[wave][c] = arow[c];
    float asi = as_[g * KK + i];
    float vals[E];
    float m = -1e30f;
#pragma unroll
    for (int e = 0; e < E; ++e) {
        int j = e * 64 + lane;
        float x = asi + adL[j];
        x = (x >= 0.f) ? x : 0.2f * x;
        x += rowL[wave][idxL[j]];       // LAMB = 1.0
        vals[e] = x; m = fmaxf(m, x);
    }
    m = wredmax(m);
    float S = 0.f;
#pragma unroll
    for (int e = 0; e < E; ++e) { vals[e] = expf(vals[e] - m); S += vals[e]; }
    S = wredsum(S);
    float inv = 1.f / S, rs = 0.f;
    float* orow = attn + ((long long)g * KK + i) * KK;
#pragma unroll
    for (int e = 0; e < E; ++e) { float p = vals[e] * inv; rs += p; orow[e * 64 + lane] = p; }
    rs = wredsum(rs);
    if (lane == 0) { dgo[g * KK + i] = rsqrtf(rs + 1.f); dio[g * KK + i] = 1.f / fmaxf(rs, 1.f); }
}

// ---------------------------------------------------------------------------
// readout: [max over rows, mean over rows] -> (G, 256)
// ---------------------------------------------------------------------------
template<int KK>
__global__ __launch_bounds__(128) void k_readout(const float* __restrict__ xk, float* __restrict__ xo) {
    int g = blockIdx.x, f = threadIdx.x;
    const float* p = xk + (long long)g * KK * 128 + f;
    float m = -1e30f, s = 0.f;
    for (int r = 0; r < KK; ++r) { float v = p[r * 128]; m = fmaxf(m, v); s += v; }
    xo[g * 256 + f] = m;
    xo[g * 256 + 128 + f] = s * (1.0f / KK);
}

// ---------------------------------------------------------------------------
// dense batched agg GEMM (fp32): C = A(KKxKK) @ [opt dinv_j *] Y(KKx128)
//  EPI 0: outH = relu(di*C + di^2*hx + bias)   EPI 1: outS_i = sum_f |hx - C*di|
// ---------------------------------------------------------------------------
template<int KK, bool SCALEY, int EPI>
__global__ __launch_bounds__(256) void k_agg(const float* __restrict__ A, const float* __restrict__ Y,
        const float* __restrict__ dg, const float* __restrict__ di_,
        const float* __restrict__ bias, const float* __restrict__ hx,
        float* __restrict__ outH, float* __restrict__ outS) {
    __shared__ float Al[64][68];
    __shared__ float Yl[64][132];
    __shared__ float red[64][17];
    constexpr int RB = KK / 64;
    int g = blockIdx.x / RB;
    int rb = blockIdx.x % RB;
    const float* Ag = A + (long long)g * KK * KK;
    const float* Yg = Y + (long long)g * KK * 128;
    int tid = threadIdx.x, tr = tid >> 4, tc = tid & 15;
    float acc[4][8] = {};
    for (int ch = 0; ch < KK / 64; ++ch) {
        for (int p = tid; p < 1024; p += 256) {
            int r = p >> 4, c4 = p & 15;
            *(float4*)&Al[r][c4 * 4] = *(const float4*)(Ag + (rb * 64 + r) * KK + ch * 64 + c4 * 4);
        }
        for (int p = tid; p < 2048; p += 256) {
            int r = p >> 5, c4 = p & 31;
            float4 v = *(const float4*)(Yg + (ch * 64 + r) * 128 + c4 * 4);
            if (SCALEY) { float sc = dg[g * KK + ch * 64 + r]; v.x *= sc; v.y *= sc; v.z *= sc; v.w *= sc; }
            *(float4*)&Yl[r][c4 * 4] = v;
        }
        __syncthreads();
        for (int k = 0; k < 64; ++k) {
            float4 w0 = *(const float4*)&Yl[k][tc * 8];
            float4 w1 = *(const float4*)&Yl[k][tc * 8 + 4];
            float w[8] = {w0.x, w0.y, w0.z, w0.w, w1.x, w1.y, w1.z, w1.w};
#pragma unroll
            for (int i = 0; i < 4; ++i) {
                float a = Al[tr * 4 + i][k];
#pragma unroll
                for (int j = 0; j < 8; ++j) acc[i][j] = fmaf(a, w[j], acc[i][j]);
            }
        }
        __syncthreads();
    }
    int i0 = rb * 64 + tr * 4;
    if (EPI == 0) {
#pragma unroll
        for (int i = 0; i < 4; ++i) {
            long long gi = (long long)g * KK + i0 + i;
            float d = dg[gi], dd = d * d;
            float4 x0 = *(const float4*)(hx + gi * 128 + tc * 8);
            float4 x1 = *(const float4*)(hx + gi * 128 + tc * 8 + 4);
            float4 b0 = *(const float4*)(bias + tc * 8);
            float4 b1 = *(const float4*)(bias + tc * 8 + 4);
            float4 o0, o1;
            o0.x = fmaxf(fmaf(d, acc[i][0], fmaf(dd, x0.x, b0.x)), 0.f);
            o0.y = fmaxf(fmaf(d, acc[i][1], fmaf(dd, x0.y, b0.y)), 0.f);
            o0.z = fmaxf(fmaf(d, acc[i][2], fmaf(dd, x0.z, b0.z)), 0.f);
            o0.w = fmaxf(fmaf(d, acc[i][3], fmaf(dd, x0.w, b0.w)), 0.f);
            o1.x = fmaxf(fmaf(d, acc[i][4], fmaf(dd, x1.x, b1.x)), 0.f);
            o1.y = fmaxf(fmaf(d, acc[i][5], fmaf(dd, x1.y, b1.y)), 0.f);
            o1.z = fmaxf(fmaf(d, acc[i][6], fmaf(dd, x1.z, b1.z)), 0.f);
            o1.w = fmaxf(fmaf(d, acc[i][7], fmaf(dd, x1.w, b1.w)), 0.f);
            *(float4*)(outH + gi * 128 + tc * 8)     = o0;
            *(float4*)(outH + gi * 128 + tc * 8 + 4) = o1;
        }
    } else {
#pragma unroll
        for (int i = 0; i < 4; ++i) {
            long long gi = (long long)g * KK + i0 + i;
            float d = di_[gi];
            float4 x0 = *(const float4*)(hx + gi * 128 + tc * 8);
            float4 x1 = *(const float4*)(hx + gi * 128 + tc * 8 + 4);
            float p = fabsf(x0.x - acc[i][0] * d) + fabsf(x0.y - acc[i][1] * d)
                    + fabsf(x0.z - acc[i][2] * d) + fabsf(x0.w - acc[i][3] * d)
                    + fabsf(x1.x - acc[i][4] * d) + fabsf(x1.y - acc[i][5] * d)
                    + fabsf(x1.z - acc[i][6] * d) + fabsf(x1.w - acc[i][7] * d);
            red[tr * 4 + i][tc] = p;
        }
        __syncthreads();
        if (tid < 64) {
            float s = 0.f;
#pragma unroll
            for (int t = 0; t < 16; ++t) s += red[tid][t];
            outS[(long long)g * KK + rb * 64 + tid] = s;
        }
    }
}

// ---------------------------------------------------------------------------
// final MLP + softmax, one block per graph
// ---------------------------------------------------------------------------
__global__ __launch_bounds__(128) void k_mlp(const float* __restrict__ x1, const float* __restrict__ x2,
        const float* __restrict__ x3,
        const float* __restrict__ Wl1, const float* __restrict__ bl1,
        const float* __restrict__ Wl2, const float* __restrict__ bl2,
        const float* __restrict__ Wl3, const float* __restrict__ bl3,
        float* __restrict__ out) {
    __shared__ float z[256], z1[128], z2[64], lg[10];
    int g = blockIdx.x, t = threadIdx.x;
    for (int k = t; k < 256; k += 128)
        z[k] = fmaxf(x1[g * 256 + k], 0.f) + fmaxf(x2[g * 256 + k], 0.f) + fmaxf(x3[g * 256 + k], 0.f);
    __syncthreads();
    {
        float acc = bl1[t];
        for (int k = 0; k < 256; ++k) acc = fmaf(z[k], Wl1[k * 128 + t], acc);
        z1[t] = fmaxf(acc, 0.f);
    }
    __syncthreads();
    if (t < 64) {
        float acc = bl2[t];
        for (int k = 0; k < 128; ++k) acc = fmaf(z1[k], Wl2[k * 64 + t], acc);
        z2[t] = fmaxf(acc, 0.f);
    }
    __syncthreads();
    if (t < 10) {
        float acc = bl3[t];
        for (int k = 0; k < 64; ++k) acc = fmaf(z2[k], Wl3[k * 10 + t], acc);
        lg[t] = acc;
    }
    __syncthreads();
    if (t == 0) {
        float m = -1e30f;
        for (int c = 0; c < 10; ++c) m = fmaxf(m, lg[c]);
        float S = 0.f;
        float e[10];
        for (int c = 0; c < 10; ++c) { e[c] = expf(lg[c] - m); S += e[c]; }
        float inv = 1.f / S;
        for (int c = 0; c < 10; ++c) out[g * 10 + c] = e[c] * inv;
    }
}

// ---------------------------------------------------------------------------
extern "C" void kernel_launch(void* const* d_in, const int* in_sizes, int n_in,
                              void* d_out, int out_size, void* d_ws, size_t ws_size,
                              hipStream_t stream) {
    const float* x     = (const float*)d_in[0];
    const float* adj   = (const float*)d_in[1];
    const float* W1    = (const float*)d_in[2];
    const float* b1    = (const float*)d_in[3];
    const float* W2    = (const float*)d_in[4];
    const float* b2    = (const float*)d_in[5];
    const float* W3    = (const float*)d_in[6];
    const float* b3    = (const float*)d_in[7];
    const float* att1s = (const float*)d_in[8];
    const float* att1d = (const float*)d_in[9];
    const float* att2s = (const float*)d_in[10];
    const float* att2d = (const float*)d_in[11];
    const float* Wl1   = (const float*)d_in[12];
    const float* bl1   = (const float*)d_in[13];
    const float* Wl2   = (const float*)d_in[14];
    const float* bl2   = (const float*)d_in[15];
    const float* Wl3   = (const float*)d_in[16];
    const float* bl3   = (const float*)d_in[17];
    float* out = (float*)d_out;

    char* ws = (char*)d_ws;
    // ---- workspace (~263 MB, no aliasing) ----
    unsigned* adjbits = (unsigned*)(ws + 0);        // 4,194,304
    ush*   T1hi   = (ush*)  (ws + 8388608);         // dxw1^T splits, 3x16 MB
    ush*   T1mid  = (ush*)  (ws + 25165824);
    ush*   T1lo   = (ush*)  (ws + 41943040);
    ush*   T2hi   = (ush*)  (ws + 58720256);        // h1^T splits
    ush*   T2mid  = (ush*)  (ws + 75497472);
    ush*   T2lo   = (ush*)  (ws + 92274688);
    float* dxw1   = (float*)(ws + 109051904);       // 33.5 MB; h1 in-place
    float* h1     = dxw1;
    float* a1     = (float*)(ws + 142606336);       // 33.5 MB
    float* xk1    = (float*)(ws + 176160768);       // 16.8 MB
    float* xw2    = (float*)(ws + 192937984);       // 16.8 MB
    float* h2     = (float*)(ws + 209715200);       // 16.8 MB
    float* xk2    = (float*)(ws + 226492416);       // 8.4 MB
    float* a2     = (float*)(ws + 234881024);       // 8.4 MB
    float* xw3    = (float*)(ws + 243269632);       // 8.4 MB
    float* h3     = (float*)(ws + 251658240);       // 8.4 MB
    float* s1     = (float*)(ws + 260046848);
    int*   idx1   = (int*)  (ws + 260308992);
    float* as1    = (float*)(ws + 260571136);
    float* ad1    = (float*)(ws + 260702208);
    float* dinv_g1= (float*)(ws + 260833280);
    float* dinv_i1= (float*)(ws + 261095424);
    float* dinv_g2= (float*)(ws + 261357568);
    float* dinv_i2= (float*)(ws + 261488640);
    float* x1r    = (float*)(ws + 261619712);
    float* s2     = (float*)(ws + 261750784);
    int*   idx2   = (int*)  (ws + 261881856);
    float* as2    = (float*)(ws + 261947392);
    float* ad2    = (float*)(ws + 262012928);
    float* dinv_g3= (float*)(ws + 262078464);
    float* dinv_i3= (float*)(ws + 262144000);
    float* x2r    = (float*)(ws + 262209536);
    float* x3r    = (float*)(ws + 262340608);

    // stage 1: full graph (N=512), bit-A MFMA aggregations
    k_prep<<<Gg * N1 / 4, 256, 0, stream>>>(adj, dinv_g1, dinv_i1, adjbits);
    k_gemm_rw<<<Gg * N1 / 64, 256, 0, stream>>>(x, W1, dxw1, dinv_g1);
    k_tsplit<<<Gg * 16, 256, 0, stream>>>(dxw1, T1hi, T1mid, T1lo);
    k_aggb<0><<<Gg * 8, 256, 0, stream>>>(adjbits, T1hi, T1mid, T1lo, dinv_g1, dxw1, b1, h1, nullptr);
    k_tsplit<<<Gg * 16, 256, 0, stream>>>(h1, T2hi, T2mid, T2lo);
    k_aggb<1><<<Gg * 8, 256, 0, stream>>>(adjbits, T2hi, T2mid, T2lo, dinv_i1, h1, nullptr, nullptr, s1);
    k_topk<N1, K1><<<Gg, 256, 0, stream>>>(s1, idx1);
    k_gather<K1><<<Gg * K1 / 4, 256, 0, stream>>>(h1, N1, idx1, att1s, att1d, xk1, as1, ad1);
    k_readout<K1><<<Gg, 128, 0, stream>>>(xk1, x1r);
    k_attn1b<<<Gg * K1 / 4, 256, 0, stream>>>(adjbits, idx1, as1, ad1, a1, dinv_g2, dinv_i2);

    // stage 2: pooled graph (K1=256), dense attention adjacency a1 (fp32 path)
    k_gemm_rw<<<Gg * K1 / 64, 256, 0, stream>>>(xk1, W2, xw2, nullptr);
    k_agg<K1, true, 0><<<Gg * (K1 / 64), 256, 0, stream>>>(a1, xw2, dinv_g2, dinv_i2, b2, xw2, h2, nullptr);
    k_agg<K1, false, 1><<<Gg * (K1 / 64), 256, 0, stream>>>(a1, h2, dinv_g2, dinv_i2, b2, h2, nullptr, s2);
    k_topk<K1, K2><<<Gg, 256, 0, stream>>>(s2, idx2);
    k_gather<K2><<<Gg * K2 / 4, 256, 0, stream>>>(h2, K1, idx2, att2s, att2d, xk2, as2, ad2);
    k_readout<K2><<<Gg, 128, 0, stream>>>(xk2, x2r);
    k_attn<K2, K1><<<Gg * K2 / 4, 256, 0, stream>>>(a1, idx2, as2, ad2, a2, dinv_g3, dinv_i3);

    // stage 3: pooled graph (K2=128)
    k_gemm_rw<<<Gg * K2 / 64, 256, 0, stream>>>(xk2, W3, xw3, nullptr);
    k_agg<K2, true, 0><<<Gg * (K2 / 64), 256, 0, stream>>>(a2, xw3, dinv_g3, dinv_i3, b3, xw3, h3, nullptr);
    k_readout<K2><<<Gg, 128, 0, stream>>>(h3, x3r);

    // final MLP
    k_mlp<<<Gg, 128, 0, stream>>>(x1r, x2r, x3r, Wl1, bl1, Wl2, bl2, Wl3, bl3, out);
}